// Round 4
// baseline (104.528 us; speedup 1.0000x reference)
//
#include <hip/hip_runtime.h>
#include <math.h>

// Problem constants
#define BB   64
#define LL   4096
#define DKC  128
#define DVC  128
#define HC   4
#define DKLC 64
#define DVLC 128
#define RC   128
#define NSPLIT 16
#define CHUNK  (LL / NSPLIT)   // 256 rows per chunk

// ---------------------------------------------------------------------------
// Kernel 0: fold q[h][d] = sum_k Wq[h,k] * Wk[d,h,k]   (H*DK = 512 values)
// ---------------------------------------------------------------------------
__global__ __launch_bounds__(512) void k_foldq(const float* __restrict__ Wq,
                                               const float* __restrict__ Wk,
                                               float* __restrict__ q) {
    int t = threadIdx.x;            // 0..511
    int h = t >> 7;                 // 0..3
    int d = t & 127;                // 0..127
    float acc = 0.f;
#pragma unroll 8
    for (int k = 0; k < DKLC; ++k)
        acc += Wq[h * DKLC + k] * Wk[(d * HC + h) * DKLC + k];
    q[h * DKC + d] = acc;
}

// ---------------------------------------------------------------------------
// Streaming kernel 1: one thread per K row (256 rows per block = one chunk).
//   sval[h] = mask ? -inf : scale * dot(K[row], q[h])   (pure register dot,
//   independent float4 load chain -> deep memory pipelining, no barriers)
//   then per-chunk per-head softmax stats (m, Z) via shuffle+LDS trees and
//   un-normalized P = exp(s - m) written coalesced.
// ---------------------------------------------------------------------------
__global__ __launch_bounds__(256) void k_score(const float* __restrict__ K,
                                               const int*   __restrict__ mask,
                                               const float* __restrict__ q,
                                               float* __restrict__ P,
                                               float* __restrict__ stats) {
    const int bid = blockIdx.x;           // b*NSPLIT + sp
    const int b   = bid >> 4;
    const int sp  = bid & (NSPLIT - 1);
    const int l0  = sp * CHUNK;
    const int t   = threadIdx.x;
    const int w   = t >> 6;               // wave id
    const int ln  = t & 63;

    __shared__ float4 qs[HC * 32];        // 2 KB (broadcast reads)
    __shared__ float  redm[HC][4];
    __shared__ float  redz[HC][4];
    __shared__ float  mh[HC];

    if (t < HC * 32) qs[t] = ((const float4*)q)[t];
    int mk = mask[(long)b * LL + l0 + t];
    __syncthreads();

    // ---- per-thread row dot (row = l0 + t) ----
    const float4* Kr = (const float4*)(K + ((long)b * LL + l0 + t) * DKC);
    float acc[HC] = {0.f, 0.f, 0.f, 0.f};
#pragma unroll 8
    for (int c = 0; c < DKC / 4; ++c) {
        float4 kv = Kr[c];
#pragma unroll
        for (int h = 0; h < HC; ++h) {
            float4 qv = qs[h * 32 + c];
            acc[h] += kv.x * qv.x + kv.y * qv.y + kv.z * qv.z + kv.w * qv.w;
        }
    }
    const float scale = 0.08838834764831844f;   // 1/sqrt(128)
    float sval[HC];
#pragma unroll
    for (int h = 0; h < HC; ++h)
        sval[h] = mk ? -INFINITY : acc[h] * scale;

    // ---- chunk max per head: wave shuffle tree, then 4-wave combine ----
    float m[HC];
#pragma unroll
    for (int h = 0; h < HC; ++h) {
        m[h] = sval[h];
#pragma unroll
        for (int off = 32; off; off >>= 1)
            m[h] = fmaxf(m[h], __shfl_xor(m[h], off));
    }
    if (ln == 0)
#pragma unroll
        for (int h = 0; h < HC; ++h) redm[h][w] = m[h];
    __syncthreads();
    if (t < HC) {
        float mm = fmaxf(fmaxf(redm[t][0], redm[t][1]),
                         fmaxf(redm[t][2], redm[t][3]));
        mh[t] = (mm == -INFINITY) ? 0.f : mm;   // all-masked guard
        stats[(long)bid * 8 + t] = mm;          // raw chunk max (may be -inf)
    }
    __syncthreads();

    // ---- P = exp(s - m), coalesced store; Z via shuffle tree ----
    float z[HC];
#pragma unroll
    for (int h = 0; h < HC; ++h) {
        float p = expf(sval[h] - mh[h]);
        P[((long)b * HC + h) * LL + l0 + t] = p;
        z[h] = p;
#pragma unroll
        for (int off = 32; off; off >>= 1)
            z[h] += __shfl_xor(z[h], off);
    }
    if (ln == 0)
#pragma unroll
        for (int h = 0; h < HC; ++h) redz[h][w] = z[h];
    __syncthreads();
    if (t < HC)
        stats[(long)bid * 8 + 4 + t] =
            redz[t][0] + redz[t][1] + redz[t][2] + redz[t][3];
}

// ---------------------------------------------------------------------------
// Streaming kernel 2: partial WV[b,sp,h,e] = sum_{l in chunk} P[b,h,l]*V[b,l,e]
// 256 threads = 8 row-groups x 32 float4-cols; P broadcast from LDS;
// free-running V stream (no barrier inside the loop).
// ---------------------------------------------------------------------------
__global__ __launch_bounds__(256) void k_wv(const float* __restrict__ V,
                                            const float* __restrict__ P,
                                            float* __restrict__ part) {
    const int bid = blockIdx.x;
    const int b   = bid >> 4;
    const int sp  = bid & (NSPLIT - 1);
    const int l0  = sp * CHUNK;
    const int t   = threadIdx.x;
    const int rg  = t >> 5;               // 0..7
    const int i4  = t & 31;               // float4 column
    const int w   = t >> 6;

    __shared__ float  wlds[HC][CHUNK];    // 4 KB
    __shared__ float4 red[4][32][HC];     // 8 KB

#pragma unroll
    for (int h = 0; h < HC; ++h)
        wlds[h][t] = P[((long)b * HC + h) * LL + l0 + t];
    __syncthreads();

    float4 acc[HC];
#pragma unroll
    for (int h = 0; h < HC; ++h) acc[h] = make_float4(0.f, 0.f, 0.f, 0.f);

    const float4* Vb = (const float4*)(V + ((long)b * LL + l0) * DVC);
#pragma unroll 4
    for (int it = 0; it < CHUNK / 8; ++it) {   // 32 iterations
        int r = it * 8 + rg;
        float4 vv = Vb[r * (DVC / 4) + i4];
#pragma unroll
        for (int h = 0; h < HC; ++h) {
            float wt = wlds[h][r];             // 2 addrs/wave -> broadcast
            acc[h].x += wt * vv.x; acc[h].y += wt * vv.y;
            acc[h].z += wt * vv.z; acc[h].w += wt * vv.w;
        }
    }
    // combine row-group pairs (rg and rg^1 live in the same wave: lane^32)
#pragma unroll
    for (int h = 0; h < HC; ++h) {
        acc[h].x += __shfl_xor(acc[h].x, 32);
        acc[h].y += __shfl_xor(acc[h].y, 32);
        acc[h].z += __shfl_xor(acc[h].z, 32);
        acc[h].w += __shfl_xor(acc[h].w, 32);
    }
    if ((t & 63) < 32) {
#pragma unroll
        for (int h = 0; h < HC; ++h) red[w][i4][h] = acc[h];
    }
    __syncthreads();
    if (t < 128) {
        int h = t >> 5, c = t & 31;
        float4 s0 = red[0][c][h], s1 = red[1][c][h];
        float4 s2 = red[2][c][h], s3 = red[3][c][h];
        float4 o;
        o.x = s0.x + s1.x + s2.x + s3.x;
        o.y = s0.y + s1.y + s2.y + s3.y;
        o.z = s0.z + s1.z + s2.z + s3.z;
        o.w = s0.w + s1.w + s2.w + s3.w;
        ((float4*)part)[((long)bid * HC + h) * (DVC / 4) + c] = o;
    }
}

// ---------------------------------------------------------------------------
// Epilogue: combine split partials (softmax rescale), then
// QKV = (1/L) * WV*Wv ; out = QKV*Wo      one block per b
// ---------------------------------------------------------------------------
__global__ __launch_bounds__(256) void k_out(const float* __restrict__ stats,
                                             const float* __restrict__ part,
                                             const float* __restrict__ Wv,
                                             const float* __restrict__ Wo,
                                             float* __restrict__ out) {
    int b = blockIdx.x;
    int t = threadIdx.x;
    __shared__ float WV[HC][DVC];        // 2 KB
    __shared__ float QKV[HC * DVLC];     // 2 KB
    __shared__ float sc[NSPLIT][HC];     // rescale factors
    __shared__ float zs[HC];

    if (t < HC) {
        float m = -INFINITY;
        for (int p = 0; p < NSPLIT; ++p)
            m = fmaxf(m, stats[((long)b * NSPLIT + p) * 8 + t]);
        float Z = 0.f;
        for (int p = 0; p < NSPLIT; ++p) {
            float s = expf(stats[((long)b * NSPLIT + p) * 8 + t] - m);
            sc[p][t] = s;
            Z += s * stats[((long)b * NSPLIT + p) * 8 + 4 + t];
        }
        zs[t] = Z;
    }
    __syncthreads();

    for (int j = t; j < HC * DVC; j += 256) {
        int h = j >> 7, e = j & 127;
        float a = 0.f;
#pragma unroll 8
        for (int p = 0; p < NSPLIT; ++p)
            a += sc[p][h] * part[(((long)b * NSPLIT + p) * HC + h) * DVC + e];
        WV[h][e] = a / zs[h];
    }
    __syncthreads();

    for (int j = t; j < HC * DVLC; j += 256) {
        int h = j >> 7, vv = j & 127;
        float a = 0.f;
#pragma unroll 8
        for (int e = 0; e < DVC; ++e)
            a += WV[h][e] * Wv[(e * HC + h) * DVLC + vv];
        QKV[j] = a * (1.0f / LL);
    }
    __syncthreads();

    for (int r = t; r < RC; r += 256) {
        float a = 0.f;
#pragma unroll 8
        for (int i = 0; i < HC * DVLC; ++i)
            a += QKV[i] * Wo[i * RC + r];
        out[b * RC + r] = a;
    }
}

// ---------------------------------------------------------------------------
extern "C" void kernel_launch(void* const* d_in, const int* in_sizes, int n_in,
                              void* d_out, int out_size, void* d_ws, size_t ws_size,
                              hipStream_t stream) {
    (void)in_sizes; (void)n_in; (void)out_size; (void)ws_size;
    const float* K    = (const float*)d_in[0];
    const float* V    = (const float*)d_in[1];
    const int*   mask = (const int*)  d_in[2];
    const float* Wq   = (const float*)d_in[3];
    const float* Wk   = (const float*)d_in[4];
    const float* Wv   = (const float*)d_in[5];
    const float* Wo   = (const float*)d_in[6];
    float* out = (float*)d_out;

    float* q     = (float*)d_ws;                          // 512 floats
    float* stats = q + 512;                               // B*NSPLIT*8 = 8192
    float* part  = stats + (long)BB * NSPLIT * 8;         // B*NSPLIT*H*DV = 524288
    float* P     = part + (long)BB * NSPLIT * HC * DVC;   // B*H*L = 1,048,576

    k_foldq<<<1, 512, 0, stream>>>(Wq, Wk, q);
    k_score<<<BB * NSPLIT, 256, 0, stream>>>(K, mask, q, P, stats);
    k_wv<<<BB * NSPLIT, 256, 0, stream>>>(V, P, part);
    k_out<<<BB, 256, 0, stream>>>(stats, part, Wv, Wo, out);
}

// Round 5
// 99.682 us; speedup vs baseline: 1.0486x; 1.0486x over previous
//
#include <hip/hip_runtime.h>
#include <math.h>

// Problem constants
#define BB   64
#define LL   4096
#define DKC  128
#define DVC  128
#define HC   4
#define DKLC 64
#define DVLC 128
#define RC   128

#define NCA  64            // score chunks per batch
#define CA   64            // rows per score chunk
#define NCB  16            // wv chunks per batch
#define CB   256           // rows per wv chunk
#define SUB  4             // score chunks per wv chunk

// ---------------------------------------------------------------------------
// Kernel 0: fold q[h][d] = sum_k Wq[h,k] * Wk[d,h,k]   (H*DK = 512 values)
// ---------------------------------------------------------------------------
__global__ __launch_bounds__(512) void k_foldq(const float* __restrict__ Wq,
                                               const float* __restrict__ Wk,
                                               float* __restrict__ q) {
    int t = threadIdx.x;            // 0..511
    int h = t >> 7;                 // 0..3
    int d = t & 127;                // 0..127
    float acc = 0.f;
#pragma unroll 8
    for (int k = 0; k < DKLC; ++k)
        acc += Wq[h * DKLC + k] * Wk[(d * HC + h) * DKLC + k];
    q[h * DKC + d] = acc;
}

// ---------------------------------------------------------------------------
// Score kernel, one block per (b, 64-row chunk):
//  phase 1: coalesced K loads -> 4-head partial dots -> padded LDS (b128)
//  phase 2: thread (row,head) sums 32 partials down a conflict-free column,
//           applies mask/scale; shuffle+LDS softmax stats (m, Z);
//           writes un-normalized P[l][h] = exp(s - m_chunk) (float4/row)
// K is read exactly once, no K staging, one barrier before phase 2.
// ---------------------------------------------------------------------------
__global__ __launch_bounds__(256) void k_score(const float* __restrict__ K,
                                               const int*   __restrict__ mask,
                                               const float* __restrict__ q,
                                               float* __restrict__ P4,
                                               float* __restrict__ stats) {
    const int bid = blockIdx.x;            // b*NCA + sp
    const int b   = bid >> 6;
    const int sp  = bid & (NCA - 1);
    const int l0  = sp * CA;
    const int t   = threadIdx.x;
    const int rg  = t >> 5;                // 0..7 row group
    const int i4  = t & 31;                // 16-B column slice

    __shared__ float4 part[CA][33];        // padded: col reads are 2-way/free
    __shared__ float  redm[4][HC];
    __shared__ float  redz[4][HC];

    // folded q fragments in registers (broadcast load per 32-lane group)
    float4 qf[HC];
#pragma unroll
    for (int h = 0; h < HC; ++h)
        qf[h] = ((const float4*)q)[h * 32 + i4];

    const float4* Kg = (const float4*)(K + ((long)b * LL + l0) * DKC);

    // ---- phase 1: coalesced K stream -> partial dots -> LDS ----
#pragma unroll
    for (int it = 0; it < CA / 8; ++it) {  // 8 iterations
        int r = it * 8 + rg;
        float4 kv = Kg[r * 32 + i4];       // wave = 2 rows x 512 B contiguous
        float4 d;
        d.x = kv.x*qf[0].x + kv.y*qf[0].y + kv.z*qf[0].z + kv.w*qf[0].w;
        d.y = kv.x*qf[1].x + kv.y*qf[1].y + kv.z*qf[1].z + kv.w*qf[1].w;
        d.z = kv.x*qf[2].x + kv.y*qf[2].y + kv.z*qf[2].z + kv.w*qf[2].w;
        d.w = kv.x*qf[3].x + kv.y*qf[3].y + kv.z*qf[3].z + kv.w*qf[3].w;
        part[r][i4] = d;
    }
    __syncthreads();

    // ---- phase 2: per-(row,head) column sum ----
    const int r2 = t >> 2;                 // 0..63 row
    const int h2 = t & 3;                  // head
    float s = 0.f;
#pragma unroll
    for (int c = 0; c < 32; ++c)
        s += ((const float*)part)[(r2 * 33 + c) * 4 + h2];   // bank-free

    int mk = mask[(long)b * LL + l0 + r2];
    const float scale = 0.08838834764831844f;   // 1/sqrt(128)
    s = mk ? -INFINITY : s * scale;

    // per-head chunk max: 16 rows per wave -> xor {4,8,16,32}, then 4-wave LDS
    float m = s;
#pragma unroll
    for (int off = 4; off <= 32; off <<= 1)
        m = fmaxf(m, __shfl_xor(m, off));
    if ((t & 63) < 4) redm[t >> 6][h2] = m;
    __syncthreads();
    float mm = fmaxf(fmaxf(redm[0][h2], redm[1][h2]),
                     fmaxf(redm[2][h2], redm[3][h2]));
    float mu = (mm == -INFINITY) ? 0.f : mm;    // all-masked chunk guard

    float p = expf(s - mu);
    float z = p;
#pragma unroll
    for (int off = 4; off <= 32; off <<= 1)
        z += __shfl_xor(z, off);
    if ((t & 63) < 4) redz[t >> 6][h2] = z;
    if (t < HC) stats[(long)bid * 8 + t] = mm;  // raw chunk max (may be -inf)
    __syncthreads();
    if (t < HC)
        stats[(long)bid * 8 + 4 + t] =
            redz[0][t] + redz[1][t] + redz[2][t] + redz[3][t];

    // P[l][h] layout: float index (b*LL+l0+r2)*4 + h2 == base + t (coalesced)
    P4[((long)b * LL + l0) * 4 + t] = p;
}

// ---------------------------------------------------------------------------
// WV kernel, one block per (b, 256-row chunk): barrier-free hot loop.
//   w4 = P4[r] (one broadcast float4 = all 4 head weights) * subchunk rescale
//   acc[h] += w4[h] * V[r][slice]   (coalesced V stream, registers only)
// Rescale: the 4 sub-chunks (64 rows each) carry different score maxes;
// f[j][h] = exp(m_a - m4) aligns them to the chunk max m4 (fmax-exact,
// recomputed identically in k_out). Guarded for all-masked sub-chunks.
// ---------------------------------------------------------------------------
__global__ __launch_bounds__(256) void k_wv(const float* __restrict__ V,
                                            const float* __restrict__ P4,
                                            const float* __restrict__ stats,
                                            float* __restrict__ partWV) {
    const int bid = blockIdx.x;            // b*NCB + spB
    const int b   = bid >> 4;
    const int spB = bid & (NCB - 1);
    const int l0  = spB * CB;
    const int t   = threadIdx.x;
    const int rg  = t >> 5;                // 0..7
    const int i4  = t & 31;
    const int w   = t >> 6;

    __shared__ float4 red[4][32][HC];      // 8 KB reduce scratch

    // per-subchunk, per-head rescale factors (redundant per thread, tiny)
    float ma[SUB][HC];
#pragma unroll
    for (int j = 0; j < SUB; ++j)
#pragma unroll
        for (int h = 0; h < HC; ++h)
            ma[j][h] = stats[((long)b * NCA + spB * SUB + j) * 8 + h];
    float4 f4[SUB];
#pragma unroll
    for (int h = 0; h < HC; ++h) {
        float m4 = fmaxf(fmaxf(ma[0][h], ma[1][h]), fmaxf(ma[2][h], ma[3][h]));
        float mu4 = (m4 == -INFINITY) ? 0.f : m4;
#pragma unroll
        for (int j = 0; j < SUB; ++j) {
            float f = (ma[j][h] == -INFINITY) ? 0.f : expf(ma[j][h] - mu4);
            ((float*)&f4[j])[h] = f;
        }
    }

    float4 acc[HC];
#pragma unroll
    for (int h = 0; h < HC; ++h) acc[h] = make_float4(0.f, 0.f, 0.f, 0.f);

    const float4* Vb = (const float4*)(V + ((long)b * LL + l0) * DVC);
    const float4* Pb = (const float4*)P4 + (long)b * LL + l0;

#pragma unroll
    for (int j = 0; j < SUB; ++j) {
        float4 fj = f4[j];
#pragma unroll 8
        for (int it = 0; it < 8; ++it) {
            int r = j * 64 + it * 8 + rg;
            float4 w4 = Pb[r];             // broadcast (2 addrs per wave)
            float4 vv = Vb[r * 32 + i4];   // coalesced: 2 x 512 B per wave
            float w0 = w4.x * fj.x, w1 = w4.y * fj.y;
            float w2 = w4.z * fj.z, w3 = w4.w * fj.w;
            acc[0].x += w0*vv.x; acc[0].y += w0*vv.y; acc[0].z += w0*vv.z; acc[0].w += w0*vv.w;
            acc[1].x += w1*vv.x; acc[1].y += w1*vv.y; acc[1].z += w1*vv.z; acc[1].w += w1*vv.w;
            acc[2].x += w2*vv.x; acc[2].y += w2*vv.y; acc[2].z += w2*vv.z; acc[2].w += w2*vv.w;
            acc[3].x += w3*vv.x; acc[3].y += w3*vv.y; acc[3].z += w3*vv.z; acc[3].w += w3*vv.w;
        }
    }

    // combine row-group pairs (rg, rg^1 are lane^32 within the same wave)
#pragma unroll
    for (int h = 0; h < HC; ++h) {
        acc[h].x += __shfl_xor(acc[h].x, 32);
        acc[h].y += __shfl_xor(acc[h].y, 32);
        acc[h].z += __shfl_xor(acc[h].z, 32);
        acc[h].w += __shfl_xor(acc[h].w, 32);
    }
    if ((t & 63) < 32) {
#pragma unroll
        for (int h = 0; h < HC; ++h) red[w][i4][h] = acc[h];
    }
    __syncthreads();
    if (t < 128) {
        int h = t >> 5, c = t & 31;
        float4 s0 = red[0][c][h], s1 = red[1][c][h];
        float4 s2 = red[2][c][h], s3 = red[3][c][h];
        float4 o;
        o.x = s0.x + s1.x + s2.x + s3.x;
        o.y = s0.y + s1.y + s2.y + s3.y;
        o.z = s0.z + s1.z + s2.z + s3.z;
        o.w = s0.w + s1.w + s2.w + s3.w;
        ((float4*)partWV)[((long)bid * HC + h) * (DVC / 4) + c] = o;
    }
}

// ---------------------------------------------------------------------------
// Epilogue: global softmax combine (rescale per wv-chunk), then
// QKV = (1/L) * WV*Wv ; out = QKV*Wo      one block per b
// ---------------------------------------------------------------------------
__global__ __launch_bounds__(256) void k_out(const float* __restrict__ stats,
                                             const float* __restrict__ partWV,
                                             const float* __restrict__ Wv,
                                             const float* __restrict__ Wo,
                                             float* __restrict__ out) {
    int b = blockIdx.x;
    int t = threadIdx.x;
    __shared__ float WV[HC][DVC];        // 2 KB
    __shared__ float QKV[HC * DVLC];     // 2 KB
    __shared__ float sc[NCB][HC];
    __shared__ float zs[HC];

    if (t < HC) {
        float mg = -INFINITY;
        for (int a = 0; a < NCA; ++a)
            mg = fmaxf(mg, stats[((long)b * NCA + a) * 8 + t]);
        float mu = (mg == -INFINITY) ? 0.f : mg;
        float Z = 0.f;
        for (int a = 0; a < NCA; ++a) {
            float mav = stats[((long)b * NCA + a) * 8 + t];
            float f = (mav == -INFINITY) ? 0.f : expf(mav - mu);
            Z += f * stats[((long)b * NCA + a) * 8 + 4 + t];
        }
        zs[t] = Z;
        for (int p = 0; p < NCB; ++p) {
            float m4 = -INFINITY;
            for (int j = 0; j < SUB; ++j)
                m4 = fmaxf(m4, stats[((long)b * NCA + p * SUB + j) * 8 + t]);
            sc[p][t] = (m4 == -INFINITY) ? 0.f : expf(m4 - mu);
        }
    }
    __syncthreads();

    for (int j = t; j < HC * DVC; j += 256) {
        int h = j >> 7, e = j & 127;
        float a = 0.f;
#pragma unroll 8
        for (int p = 0; p < NCB; ++p)
            a += sc[p][h] * partWV[(((long)b * NCB + p) * HC + h) * DVC + e];
        WV[h][e] = a / zs[h];
    }
    __syncthreads();

    for (int j = t; j < HC * DVLC; j += 256) {
        int h = j >> 7, vv = j & 127;
        float a = 0.f;
#pragma unroll 8
        for (int e = 0; e < DVC; ++e)
            a += WV[h][e] * Wv[(e * HC + h) * DVLC + vv];
        QKV[j] = a * (1.0f / LL);
    }
    __syncthreads();

    for (int r = t; r < RC; r += 256) {
        float a = 0.f;
#pragma unroll 8
        for (int i = 0; i < HC * DVLC; ++i)
            a += QKV[i] * Wo[i * RC + r];
        out[b * RC + r] = a;
    }
}

// ---------------------------------------------------------------------------
extern "C" void kernel_launch(void* const* d_in, const int* in_sizes, int n_in,
                              void* d_out, int out_size, void* d_ws, size_t ws_size,
                              hipStream_t stream) {
    (void)in_sizes; (void)n_in; (void)out_size; (void)ws_size;
    const float* K    = (const float*)d_in[0];
    const float* V    = (const float*)d_in[1];
    const int*   mask = (const int*)  d_in[2];
    const float* Wq   = (const float*)d_in[3];
    const float* Wk   = (const float*)d_in[4];
    const float* Wv   = (const float*)d_in[5];
    const float* Wo   = (const float*)d_in[6];
    float* out = (float*)d_out;

    float* q      = (float*)d_ws;                         // 512
    float* stats  = q + 512;                              // B*NCA*8   = 32768
    float* partWV = stats + (long)BB * NCA * 8;           // B*NCB*H*DV = 524288
    float* P4     = partWV + (long)BB * NCB * HC * DVC;   // B*L*H     = 1,048,576

    k_foldq<<<1, 512, 0, stream>>>(Wq, Wk, q);
    k_score<<<BB * NCA, 256, 0, stream>>>(K, mask, q, P4, stats);
    k_wv<<<BB * NCB, 256, 0, stream>>>(V, P4, stats, partWV);
    k_out<<<BB, 256, 0, stream>>>(stats, partWV, Wv, Wo, out);
}

// Round 6
// 79.893 us; speedup vs baseline: 1.3084x; 1.2477x over previous
//
#include <hip/hip_runtime.h>
#include <math.h>

// Problem constants
#define BB   64
#define LL   4096
#define DKC  128
#define DVC  128
#define HC   4
#define DKLC 64
#define DVLC 128
#define RC   128

#define NCA  64            // score chunks per batch
#define CA   64            // rows per score chunk
#define NCB  16            // wv chunks per batch
#define CB   256           // rows per wv chunk
#define SUB  4             // score chunks per wv chunk

// Nontemporal float4 load (bypass L2/L3 allocation for streamed-once data)
typedef float f4v __attribute__((ext_vector_type(4)));
__device__ __forceinline__ float4 ntload4(const float4* p) {
    f4v v = __builtin_nontemporal_load((const f4v*)p);
    return make_float4(v.x, v.y, v.z, v.w);
}

// ---------------------------------------------------------------------------
// Kernel 0: fold q[h][d] = sum_k Wq[h,k] * Wk[d,h,k]   (H*DK = 512 values)
// ---------------------------------------------------------------------------
__global__ __launch_bounds__(512) void k_foldq(const float* __restrict__ Wq,
                                               const float* __restrict__ Wk,
                                               float* __restrict__ q) {
    int t = threadIdx.x;            // 0..511
    int h = t >> 7;                 // 0..3
    int d = t & 127;                // 0..127
    float acc = 0.f;
#pragma unroll 8
    for (int k = 0; k < DKLC; ++k)
        acc += Wq[h * DKLC + k] * Wk[(d * HC + h) * DKLC + k];
    q[h * DKC + d] = acc;
}

// ---------------------------------------------------------------------------
// Score kernel, one block per (b, 64-row chunk):
//  phase 1: coalesced NONTEMPORAL K loads -> 4-head partial dots -> padded LDS
//  phase 2: per-(row,head) conflict-free column sum; shuffle softmax stats;
//           writes un-normalized P[l][h] = exp(s - m_chunk) (cached: reused)
// ---------------------------------------------------------------------------
__global__ __launch_bounds__(256) void k_score(const float* __restrict__ K,
                                               const int*   __restrict__ mask,
                                               const float* __restrict__ q,
                                               float* __restrict__ P4,
                                               float* __restrict__ stats) {
    const int bid = blockIdx.x;            // b*NCA + sp
    const int b   = bid >> 6;
    const int sp  = bid & (NCA - 1);
    const int l0  = sp * CA;
    const int t   = threadIdx.x;
    const int rg  = t >> 5;                // 0..7 row group
    const int i4  = t & 31;                // 16-B column slice

    __shared__ float4 part[CA][33];        // padded: col reads are 2-way/free
    __shared__ float  redm[4][HC];
    __shared__ float  redz[4][HC];

    // folded q fragments in registers (broadcast load per 32-lane group)
    float4 qf[HC];
#pragma unroll
    for (int h = 0; h < HC; ++h)
        qf[h] = ((const float4*)q)[h * 32 + i4];

    const float4* Kg = (const float4*)(K + ((long)b * LL + l0) * DKC);

    // ---- phase 1: coalesced NT K stream -> partial dots -> LDS ----
#pragma unroll
    for (int it = 0; it < CA / 8; ++it) {  // 8 iterations
        int r = it * 8 + rg;
        float4 kv = ntload4(&Kg[r * 32 + i4]);  // wave = 2 rows x 512 B
        float4 d;
        d.x = kv.x*qf[0].x + kv.y*qf[0].y + kv.z*qf[0].z + kv.w*qf[0].w;
        d.y = kv.x*qf[1].x + kv.y*qf[1].y + kv.z*qf[1].z + kv.w*qf[1].w;
        d.z = kv.x*qf[2].x + kv.y*qf[2].y + kv.z*qf[2].z + kv.w*qf[2].w;
        d.w = kv.x*qf[3].x + kv.y*qf[3].y + kv.z*qf[3].z + kv.w*qf[3].w;
        part[r][i4] = d;
    }
    __syncthreads();

    // ---- phase 2: per-(row,head) column sum ----
    const int r2 = t >> 2;                 // 0..63 row
    const int h2 = t & 3;                  // head
    float s = 0.f;
#pragma unroll
    for (int c = 0; c < 32; ++c)
        s += ((const float*)part)[(r2 * 33 + c) * 4 + h2];   // 2-way = free

    int mk = __builtin_nontemporal_load(mask + (long)b * LL + l0 + r2);
    const float scale = 0.08838834764831844f;   // 1/sqrt(128)
    s = mk ? -INFINITY : s * scale;

    // per-head chunk max: 16 rows per wave -> xor {4,8,16,32}, then 4-wave LDS
    float m = s;
#pragma unroll
    for (int off = 4; off <= 32; off <<= 1)
        m = fmaxf(m, __shfl_xor(m, off));
    if ((t & 63) < 4) redm[t >> 6][h2] = m;
    __syncthreads();
    float mm = fmaxf(fmaxf(redm[0][h2], redm[1][h2]),
                     fmaxf(redm[2][h2], redm[3][h2]));
    float mu = (mm == -INFINITY) ? 0.f : mm;    // all-masked chunk guard

    float p = expf(s - mu);
    float z = p;
#pragma unroll
    for (int off = 4; off <= 32; off <<= 1)
        z += __shfl_xor(z, off);
    if ((t & 63) < 4) redz[t >> 6][h2] = z;
    if (t < HC) stats[(long)bid * 8 + t] = mm;  // raw chunk max (may be -inf)
    __syncthreads();
    if (t < HC)
        stats[(long)bid * 8 + 4 + t] =
            redz[0][t] + redz[1][t] + redz[2][t] + redz[3][t];

    // P[l][h] layout: float index (b*LL+l0+r2)*4 + h2 == base + t (coalesced)
    P4[((long)b * LL + l0) * 4 + t] = p;
}

// ---------------------------------------------------------------------------
// WV kernel, one block per (b, 256-row chunk): barrier-free hot loop.
//   w4 = P4[r] (one broadcast float4 = all 4 head weights) * subchunk rescale
//   acc[h] += w4[h] * V[r][slice]   (NONTEMPORAL coalesced V stream)
// ---------------------------------------------------------------------------
__global__ __launch_bounds__(256) void k_wv(const float* __restrict__ V,
                                            const float* __restrict__ P4,
                                            const float* __restrict__ stats,
                                            float* __restrict__ partWV) {
    const int bid = blockIdx.x;            // b*NCB + spB
    const int b   = bid >> 4;
    const int spB = bid & (NCB - 1);
    const int l0  = spB * CB;
    const int t   = threadIdx.x;
    const int rg  = t >> 5;                // 0..7
    const int i4  = t & 31;
    const int w   = t >> 6;

    __shared__ float4 red[4][32][HC];      // 8 KB reduce scratch

    // per-subchunk, per-head rescale factors (redundant per thread, tiny)
    float ma[SUB][HC];
#pragma unroll
    for (int j = 0; j < SUB; ++j)
#pragma unroll
        for (int h = 0; h < HC; ++h)
            ma[j][h] = stats[((long)b * NCA + spB * SUB + j) * 8 + h];
    float4 f4[SUB];
#pragma unroll
    for (int h = 0; h < HC; ++h) {
        float m4 = fmaxf(fmaxf(ma[0][h], ma[1][h]), fmaxf(ma[2][h], ma[3][h]));
        float mu4 = (m4 == -INFINITY) ? 0.f : m4;
#pragma unroll
        for (int j = 0; j < SUB; ++j) {
            float f = (ma[j][h] == -INFINITY) ? 0.f : expf(ma[j][h] - mu4);
            ((float*)&f4[j])[h] = f;
        }
    }

    float4 acc[HC];
#pragma unroll
    for (int h = 0; h < HC; ++h) acc[h] = make_float4(0.f, 0.f, 0.f, 0.f);

    const float4* Vb = (const float4*)(V + ((long)b * LL + l0) * DVC);
    const float4* Pb = (const float4*)P4 + (long)b * LL + l0;

#pragma unroll
    for (int j = 0; j < SUB; ++j) {
        float4 fj = f4[j];
#pragma unroll 8
        for (int it = 0; it < 8; ++it) {
            int r = j * 64 + it * 8 + rg;
            float4 w4 = Pb[r];                    // broadcast (cached, reused)
            float4 vv = ntload4(&Vb[r * 32 + i4]); // NT: 2 x 512 B per wave
            float w0 = w4.x * fj.x, w1 = w4.y * fj.y;
            float w2 = w4.z * fj.z, w3 = w4.w * fj.w;
            acc[0].x += w0*vv.x; acc[0].y += w0*vv.y; acc[0].z += w0*vv.z; acc[0].w += w0*vv.w;
            acc[1].x += w1*vv.x; acc[1].y += w1*vv.y; acc[1].z += w1*vv.z; acc[1].w += w1*vv.w;
            acc[2].x += w2*vv.x; acc[2].y += w2*vv.y; acc[2].z += w2*vv.z; acc[2].w += w2*vv.w;
            acc[3].x += w3*vv.x; acc[3].y += w3*vv.y; acc[3].z += w3*vv.z; acc[3].w += w3*vv.w;
        }
    }

    // combine row-group pairs (rg, rg^1 are lane^32 within the same wave)
#pragma unroll
    for (int h = 0; h < HC; ++h) {
        acc[h].x += __shfl_xor(acc[h].x, 32);
        acc[h].y += __shfl_xor(acc[h].y, 32);
        acc[h].z += __shfl_xor(acc[h].z, 32);
        acc[h].w += __shfl_xor(acc[h].w, 32);
    }
    if ((t & 63) < 32) {
#pragma unroll
        for (int h = 0; h < HC; ++h) red[w][i4][h] = acc[h];
    }
    __syncthreads();
    if (t < 128) {
        int h = t >> 5, c = t & 31;
        float4 s0 = red[0][c][h], s1 = red[1][c][h];
        float4 s2 = red[2][c][h], s3 = red[3][c][h];
        float4 o;
        o.x = s0.x + s1.x + s2.x + s3.x;
        o.y = s0.y + s1.y + s2.y + s3.y;
        o.z = s0.z + s1.z + s2.z + s3.z;
        o.w = s0.w + s1.w + s2.w + s3.w;
        ((float4*)partWV)[((long)bid * HC + h) * (DVC / 4) + c] = o;
    }
}

// ---------------------------------------------------------------------------
// Epilogue (parallel stats): wave = head, lane = score chunk.
// Then WV combine + two tiny GEMMs. One block per b.
// ---------------------------------------------------------------------------
__global__ __launch_bounds__(256) void k_out(const float* __restrict__ stats,
                                             const float* __restrict__ partWV,
                                             const float* __restrict__ Wv,
                                             const float* __restrict__ Wo,
                                             float* __restrict__ out) {
    int b = blockIdx.x;
    int t = threadIdx.x;
    __shared__ float WV[HC][DVC];        // 2 KB
    __shared__ float QKV[HC * DVLC];     // 2 KB
    __shared__ float sc[NCB][HC];
    __shared__ float zinv[HC];

    // wave h2 = head, lane a = score-chunk index (NCA = 64 = wave width)
    {
        int h2 = t >> 6, a = t & 63;
        float ma = stats[((long)b * NCA + a) * 8 + h2];
        float za = stats[((long)b * NCA + a) * 8 + 4 + h2];
        float m = ma;
#pragma unroll
        for (int off = 32; off; off >>= 1) m = fmaxf(m, __shfl_xor(m, off));
        // l=0 is never masked -> m finite, Z > 0
        float f  = (ma == -INFINITY) ? 0.f : expf(ma - m);
        float fz = f * za;
#pragma unroll
        for (int off = 32; off; off >>= 1) fz += __shfl_xor(fz, off);
        // per-wv-chunk (groups of SUB=4 lanes) max -> rescale factor
        float m4 = ma;
        m4 = fmaxf(m4, __shfl_xor(m4, 1));
        m4 = fmaxf(m4, __shfl_xor(m4, 2));
        if ((a & 3) == 0) sc[a >> 2][h2] = (m4 == -INFINITY) ? 0.f : expf(m4 - m);
        if (a == 0) zinv[h2] = 1.0f / fz;
    }
    __syncthreads();

    for (int j = t; j < HC * DVC; j += 256) {
        int h = j >> 7, e = j & 127;
        float a = 0.f;
#pragma unroll 8
        for (int p = 0; p < NCB; ++p)
            a += sc[p][h] * partWV[(((long)b * NCB + p) * HC + h) * DVC + e];
        WV[h][e] = a * zinv[h];
    }
    __syncthreads();

    for (int j = t; j < HC * DVLC; j += 256) {
        int h = j >> 7, vv = j & 127;
        float a = 0.f;
#pragma unroll 8
        for (int e = 0; e < DVC; ++e)
            a += WV[h][e] * Wv[(e * HC + h) * DVLC + vv];
        QKV[j] = a * (1.0f / LL);
    }
    __syncthreads();

    for (int r = t; r < RC; r += 256) {
        float a = 0.f;
#pragma unroll 8
        for (int i = 0; i < HC * DVLC; ++i)
            a += QKV[i] * Wo[i * RC + r];
        out[b * RC + r] = a;
    }
}

// ---------------------------------------------------------------------------
extern "C" void kernel_launch(void* const* d_in, const int* in_sizes, int n_in,
                              void* d_out, int out_size, void* d_ws, size_t ws_size,
                              hipStream_t stream) {
    (void)in_sizes; (void)n_in; (void)out_size; (void)ws_size;
    const float* K    = (const float*)d_in[0];
    const float* V    = (const float*)d_in[1];
    const int*   mask = (const int*)  d_in[2];
    const float* Wq   = (const float*)d_in[3];
    const float* Wk   = (const float*)d_in[4];
    const float* Wv   = (const float*)d_in[5];
    const float* Wo   = (const float*)d_in[6];
    float* out = (float*)d_out;

    float* q      = (float*)d_ws;                         // 512
    float* stats  = q + 512;                              // B*NCA*8   = 32768
    float* partWV = stats + (long)BB * NCA * 8;           // B*NCB*H*DV = 524288
    float* P4     = partWV + (long)BB * NCB * HC * DVC;   // B*L*H     = 1,048,576

    k_foldq<<<1, 512, 0, stream>>>(Wq, Wk, q);
    k_score<<<BB * NCA, 256, 0, stream>>>(K, mask, q, P4, stats);
    k_wv<<<BB * NCB, 256, 0, stream>>>(V, P4, stats, partWV);
    k_out<<<BB, 256, 0, stream>>>(stats, partWV, Wv, Wo, out);
}

// Round 7
// 77.864 us; speedup vs baseline: 1.3424x; 1.0261x over previous
//
#include <hip/hip_runtime.h>
#include <math.h>

// Problem constants
#define BB   64
#define LL   4096
#define DKC  128
#define DVC  128
#define HC   4
#define DKLC 64
#define DVLC 128
#define RC   128

#define NCA  64            // chunks per batch
#define CA   64            // rows per chunk

// Nontemporal float4 load (bypass cache allocation for streamed-once data)
typedef float f4v __attribute__((ext_vector_type(4)));
__device__ __forceinline__ float4 ntload4(const float4* p) {
    f4v v = __builtin_nontemporal_load((const f4v*)p);
    return make_float4(v.x, v.y, v.z, v.w);
}

// ---------------------------------------------------------------------------
// Kernel 0: fold q[h][d] = sum_k Wq[h,k] * Wk[d,h,k]   (H*DK = 512 values)
// ---------------------------------------------------------------------------
__global__ __launch_bounds__(512) void k_foldq(const float* __restrict__ Wq,
                                               const float* __restrict__ Wk,
                                               float* __restrict__ q) {
    int t = threadIdx.x;            // 0..511
    int h = t >> 7;                 // 0..3
    int d = t & 127;                // 0..127
    float acc = 0.f;
#pragma unroll 8
    for (int k = 0; k < DKLC; ++k)
        acc += Wq[h * DKLC + k] * Wk[(d * HC + h) * DKLC + k];
    q[h * DKC + d] = acc;
}

// ---------------------------------------------------------------------------
// Fused score+WV kernel, one block per (b, 64-row chunk):
//  phase 1: NT K stream -> 4-head partial dots over 32-B slices -> LDS
//  phase 2: per-(row,head) 16-col sum (2-way banks = free), mask/scale,
//           in-wave softmax stats (m, Z), P -> LDS (chunk-local, exact)
//  phase 3: NT V stream -> acc[h] += P[r][h] * V[r][slice] -> partial WV
//  K and V each read exactly once; P never leaves the block.
// ---------------------------------------------------------------------------
__global__ __launch_bounds__(256) void k_fused(const float* __restrict__ K,
                                               const float* __restrict__ V,
                                               const int*   __restrict__ mask,
                                               const float* __restrict__ q,
                                               float* __restrict__ stats,
                                               float* __restrict__ partWV) {
    const int bid = blockIdx.x;            // b*NCA + a
    const int b   = bid >> 6;
    const int a   = bid & (NCA - 1);
    const int l0  = a * CA;
    const int t   = threadIdx.x;

    __shared__ float4 partS[CA][17];       // 17.4 KB; aliased as `red` later
    __shared__ float  P4s[CA * HC];        // 1 KB: P[r][h] at r*4+h
    __shared__ float  redm[4][HC];
    __shared__ float  redz[4][HC];

    // ---- phase 1: NT K stream -> partial dots (32-B slices) ----
    {
        const int rg = t >> 4;             // 0..15 row group
        const int i8 = t & 15;             // 32-B column slice
        float4 qf1[HC], qf2[HC];
#pragma unroll
        for (int h = 0; h < HC; ++h) {
            qf1[h] = ((const float4*)q)[h * 32 + i8];
            qf2[h] = ((const float4*)q)[h * 32 + i8 + 16];
        }
        const float4* Kg = (const float4*)(K + ((long)b * LL + l0) * DKC);
#pragma unroll
        for (int it = 0; it < CA / 16; ++it) {   // 4 iterations
            int r = it * 16 + rg;
            float4 k1 = ntload4(&Kg[r * 32 + i8]);        // 4x256B segs/wave
            float4 k2 = ntload4(&Kg[r * 32 + i8 + 16]);
            float4 d;
            d.x = k1.x*qf1[0].x + k1.y*qf1[0].y + k1.z*qf1[0].z + k1.w*qf1[0].w
                + k2.x*qf2[0].x + k2.y*qf2[0].y + k2.z*qf2[0].z + k2.w*qf2[0].w;
            d.y = k1.x*qf1[1].x + k1.y*qf1[1].y + k1.z*qf1[1].z + k1.w*qf1[1].w
                + k2.x*qf2[1].x + k2.y*qf2[1].y + k2.z*qf2[1].z + k2.w*qf2[1].w;
            d.z = k1.x*qf1[2].x + k1.y*qf1[2].y + k1.z*qf1[2].z + k1.w*qf1[2].w
                + k2.x*qf2[2].x + k2.y*qf2[2].y + k2.z*qf2[2].z + k2.w*qf2[2].w;
            d.w = k1.x*qf1[3].x + k1.y*qf1[3].y + k1.z*qf1[3].z + k1.w*qf1[3].w
                + k2.x*qf2[3].x + k2.y*qf2[3].y + k2.z*qf2[3].z + k2.w*qf2[3].w;
            partS[r][i8] = d;
        }
    }
    __syncthreads();

    // ---- phase 2: per-(row,head) column sum + softmax stats ----
    {
        const int r2 = t >> 2;             // 0..63 row
        const int h2 = t & 3;              // head
        float s = 0.f;
#pragma unroll
        for (int c = 0; c < 16; ++c)
            s += ((const float*)partS)[(r2 * 17 + c) * 4 + h2];  // 2-way=free

        int mk = __builtin_nontemporal_load(mask + (long)b * LL + l0 + r2);
        const float scale = 0.08838834764831844f;   // 1/sqrt(128)
        s = mk ? -INFINITY : s * scale;

        // per-head chunk max: rows of this wave -> xor {4,8,16,32} + 4-wave LDS
        float m = s;
#pragma unroll
        for (int off = 4; off <= 32; off <<= 1)
            m = fmaxf(m, __shfl_xor(m, off));
        if ((t & 63) < 4) redm[t >> 6][h2] = m;
        __syncthreads();
        float mm = fmaxf(fmaxf(redm[0][h2], redm[1][h2]),
                         fmaxf(redm[2][h2], redm[3][h2]));
        float mu = (mm == -INFINITY) ? 0.f : mm;    // all-masked chunk guard

        float p = expf(s - mu);
        float z = p;
#pragma unroll
        for (int off = 4; off <= 32; off <<= 1)
            z += __shfl_xor(z, off);
        if ((t & 63) < 4) redz[t >> 6][h2] = z;
        P4s[t] = p;                         // P[r2][h2], index == t
        if (t < HC) stats[(long)bid * 8 + t] = mm;
        __syncthreads();
        if (t < HC)
            stats[(long)bid * 8 + 4 + t] =
                redz[0][t] + redz[1][t] + redz[2][t] + redz[3][t];
    }

    // ---- phase 3: NT V stream, acc[h] += P[r][h] * V[r][slice] ----
    const int rg3 = t >> 5;                // 0..7
    const int i4  = t & 31;
    const int w   = t >> 6;
    float4 acc[HC];
#pragma unroll
    for (int h = 0; h < HC; ++h) acc[h] = make_float4(0.f, 0.f, 0.f, 0.f);

    const float4* Vb = (const float4*)(V + ((long)b * LL + l0) * DVC);
#pragma unroll
    for (int it = 0; it < CA / 8; ++it) {  // 8 iterations
        int r = it * 8 + rg3;
        float4 vv = ntload4(&Vb[r * 32 + i4]);        // 2 x 512 B per wave
        float4 w4 = ((const float4*)P4s)[r];          // broadcast (2 addrs)
        acc[0].x += w4.x*vv.x; acc[0].y += w4.x*vv.y; acc[0].z += w4.x*vv.z; acc[0].w += w4.x*vv.w;
        acc[1].x += w4.y*vv.x; acc[1].y += w4.y*vv.y; acc[1].z += w4.y*vv.z; acc[1].w += w4.y*vv.w;
        acc[2].x += w4.z*vv.x; acc[2].y += w4.z*vv.y; acc[2].z += w4.z*vv.z; acc[2].w += w4.z*vv.w;
        acc[3].x += w4.w*vv.x; acc[3].y += w4.w*vv.y; acc[3].z += w4.w*vv.z; acc[3].w += w4.w*vv.w;
    }
    // combine row-group pairs (rg3, rg3^1 are lane^32 within the same wave)
#pragma unroll
    for (int h = 0; h < HC; ++h) {
        acc[h].x += __shfl_xor(acc[h].x, 32);
        acc[h].y += __shfl_xor(acc[h].y, 32);
        acc[h].z += __shfl_xor(acc[h].z, 32);
        acc[h].w += __shfl_xor(acc[h].w, 32);
    }
    // 4 remaining row groups -> LDS (aliased over dead partS) -> final sum
    float4 (*red)[32][HC] = (float4 (*)[32][HC])partS;   // 8 KB < 17.4 KB
    __syncthreads();                       // partS reads all done (2 bars ago)
    if ((t & 63) < 32) {
#pragma unroll
        for (int h = 0; h < HC; ++h) red[w][i4][h] = acc[h];
    }
    __syncthreads();
    if (t < 128) {
        int h = t >> 5, c = t & 31;
        float4 s0 = red[0][c][h], s1 = red[1][c][h];
        float4 s2 = red[2][c][h], s3 = red[3][c][h];
        float4 o;
        o.x = s0.x + s1.x + s2.x + s3.x;
        o.y = s0.y + s1.y + s2.y + s3.y;
        o.z = s0.z + s1.z + s2.z + s3.z;
        o.w = s0.w + s1.w + s2.w + s3.w;
        ((float4*)partWV)[((long)bid * HC + h) * (DVC / 4) + c] = o;
    }
}

// ---------------------------------------------------------------------------
// Epilogue: combine 64 chunk-partials per b (wave = head, lane = chunk),
// then QKV = (1/L) WV*Wv ; out = QKV*Wo.   One block per b.
// ---------------------------------------------------------------------------
__global__ __launch_bounds__(256) void k_out(const float* __restrict__ stats,
                                             const float* __restrict__ partWV,
                                             const float* __restrict__ Wv,
                                             const float* __restrict__ Wo,
                                             float* __restrict__ out) {
    int b = blockIdx.x;
    int t = threadIdx.x;
    __shared__ float WV[HC][DVC];        // 2 KB
    __shared__ float QKV[HC * DVLC];     // 2 KB
    __shared__ float sc[NCA][HC];        // 1 KB rescale factors
    __shared__ float zinv[HC];

    // wave h2 = head, lane a = chunk (NCA = 64 = wave width)
    {
        int h2 = t >> 6, a = t & 63;
        float ma = stats[((long)b * NCA + a) * 8 + h2];
        float za = stats[((long)b * NCA + a) * 8 + 4 + h2];
        float m = ma;
#pragma unroll
        for (int off = 32; off; off >>= 1) m = fmaxf(m, __shfl_xor(m, off));
        // l=0 is never masked -> m finite, Z > 0
        float f  = (ma == -INFINITY) ? 0.f : expf(ma - m);
        sc[a][h2] = f;
        float fz = f * za;
#pragma unroll
        for (int off = 32; off; off >>= 1) fz += __shfl_xor(fz, off);
        if (a == 0) zinv[h2] = 1.0f / fz;
    }
    __syncthreads();

    for (int j = t; j < HC * DVC; j += 256) {
        int h = j >> 7, e = j & 127;
        float acc = 0.f;
#pragma unroll 8
        for (int p = 0; p < NCA; ++p)
            acc += sc[p][h] * partWV[(((long)b * NCA + p) * HC + h) * DVC + e];
        WV[h][e] = acc * zinv[h];
    }
    __syncthreads();

    for (int j = t; j < HC * DVLC; j += 256) {
        int h = j >> 7, vv = j & 127;
        float acc = 0.f;
#pragma unroll 8
        for (int e = 0; e < DVC; ++e)
            acc += WV[h][e] * Wv[(e * HC + h) * DVLC + vv];
        QKV[j] = acc * (1.0f / LL);
    }
    __syncthreads();

    for (int r = t; r < RC; r += 256) {
        float acc = 0.f;
#pragma unroll 8
        for (int i = 0; i < HC * DVLC; ++i)
            acc += QKV[i] * Wo[i * RC + r];
        out[b * RC + r] = acc;
    }
}

// ---------------------------------------------------------------------------
extern "C" void kernel_launch(void* const* d_in, const int* in_sizes, int n_in,
                              void* d_out, int out_size, void* d_ws, size_t ws_size,
                              hipStream_t stream) {
    (void)in_sizes; (void)n_in; (void)out_size; (void)ws_size;
    const float* K    = (const float*)d_in[0];
    const float* V    = (const float*)d_in[1];
    const int*   mask = (const int*)  d_in[2];
    const float* Wq   = (const float*)d_in[3];
    const float* Wk   = (const float*)d_in[4];
    const float* Wv   = (const float*)d_in[5];
    const float* Wo   = (const float*)d_in[6];
    float* out = (float*)d_out;

    float* q      = (float*)d_ws;                         // 512
    float* stats  = q + 512;                              // B*NCA*8   = 32768
    float* partWV = stats + (long)BB * NCA * 8;           // B*NCA*H*DV = 2M floats

    k_foldq<<<1, 512, 0, stream>>>(Wq, Wk, q);
    k_fused<<<BB * NCA, 256, 0, stream>>>(K, V, mask, q, stats, partWV);
    k_out<<<BB, 256, 0, stream>>>(stats, partWV, Wv, Wo, out);
}